// Round 6
// baseline (362.398 us; speedup 1.0000x reference)
//
#include <hip/hip_runtime.h>

#define NV 8192
#define NH 4096
#define TPB 256
#define HPB 8                      // h rows per block: 16 float4 loads per thread
#define HCH (NH / HPB)             // 512 h-chunks (gridDim.y)
#define ROW4 (NV / 4)              // 2048 float4 per row
#define VBLK (ROW4 / TPB)          // 8 blocks in x
#define WPB (TPB / 64)             // 4 waves per block
#define NSLOT (VBLK * HCH * WPB)   // 16384 per-wave trace partials (64 KB ws)

typedef float f32x4 __attribute__((ext_vector_type(4)));  // native vec for nontemporal store

// output layout (flat float offsets, reference return order)
#define OFF_B   ((size_t)0)
#define OFF_WT  ((size_t)NV)
#define OFF_SIG ((size_t)NV + (size_t)NH * (size_t)NV)
#define OFF_MUH (OFF_SIG + 1)
#define OFF_VHD (OFF_MUH + NH)

__global__ __launch_bounds__(TPB) void init_k(
    const float* __restrict__ muvTE,
    const float* __restrict__ varh_diagTE,
    const float* __restrict__ muhTE,
    float* __restrict__ out)
{
    int i = blockIdx.x * TPB + threadIdx.x;     // grid covers NV
    if (i < NV) out[OFF_B + i] = muvTE[i];
    if (i < NH) {
        out[OFF_MUH + i] = muhTE[i];
        out[OFF_VHD + i] = varh_diagTE[i];
    }
}

// BARRIER-FREE main_k. Previous rounds all ended with atomics + __syncthreads,
// and the compiler emits s_waitcnt vmcnt(0) before s_barrier -> every block
// drained its nt-stores AND 512-way-contended atomics before retiring. That
// tail was the round-invariant; body changes (occupancy/MLP/order) were all
// null. This version has NO __syncthreads and NO LDS:
//  - coefs from block-uniform scalar loads, computed under vmem-load shadow
//  - trace partial per WAVE (shuffle-reduce + lane-0 store, no LDS step)
//  - atomics issue last and retire after s_endpgm, off the critical path
__global__ __launch_bounds__(TPB, 4) void main_k(
    const float4* __restrict__ varvhTE4,
    const float4* __restrict__ varvh4,
    const float* __restrict__ varh_diagTE,
    const float* __restrict__ varh_diag,
    const float* __restrict__ muh,
    const float* __restrict__ muhTE,
    float* __restrict__ out,
    float* __restrict__ tr_partial)
{
    const int t  = threadIdx.x;
    const int h0 = blockIdx.y * HPB;
    const int v4 = blockIdx.x * TPB + t;        // float4 column index
    f32x4* wt4 = (f32x4*)(out + OFF_WT);
    const size_t base = (size_t)h0 * ROW4 + (size_t)v4;

    // ---- phase 1: issue ALL 16 vector loads (64 data VGPRs) ----
    float4 aTE_r[HPB], a_r[HPB];
    #pragma unroll
    for (int r = 0; r < HPB; ++r) {
        size_t idx = base + (size_t)r * ROW4;
        aTE_r[r] = varvhTE4[idx];
        a_r[r]   = varvh4[idx];
    }

    // per-h coefficients {inv, inv*muh, d*muh - inv*muhTE, d}: addresses are
    // block-uniform -> s_load + VALU, fully hidden under the vmem latency.
    float4 cf[HPB];
    #pragma unroll
    for (int r = 0; r < HPB; ++r) {
        float inv = 1.0f / varh_diag[h0 + r];
        float d   = inv * varh_diagTE[h0 + r] * inv;
        float m   = muh[h0 + r];
        cf[r] = make_float4(inv, inv * m, d * m - inv * muhTE[h0 + r], d);
    }

    // loads may not sink below; compute consumes laundered defs (counted vmcnt)
    asm volatile("" ::: "memory");
    #pragma unroll
    for (int r = 0; r < HPB; ++r) {
        asm volatile("" : "+v"(aTE_r[r].x), "+v"(aTE_r[r].y),
                          "+v"(aTE_r[r].z), "+v"(aTE_r[r].w));
        asm volatile("" : "+v"(a_r[r].x), "+v"(a_r[r].y),
                          "+v"(a_r[r].z), "+v"(a_r[r].w));
    }

    // ---- phase 2: compute + store ----
    float bx = 0.f, by = 0.f, bz = 0.f, bw = 0.f;
    float tr = 0.f;

    #pragma unroll
    for (int r = 0; r < HPB; ++r) {
        float4 c   = cf[r];
        float4 aTE = aTE_r[r];
        float4 a   = a_r[r];
        size_t idx = base + (size_t)r * ROW4;

        f32x4 w;
        w.x = c.x * aTE.x - c.w * a.x;
        w.y = c.x * aTE.y - c.w * a.y;
        w.z = c.x * aTE.z - c.w * a.z;
        w.w = c.x * aTE.w - c.w * a.w;
        __builtin_nontemporal_store(w, &wt4[idx]);

        bx += c.z * a.x - c.y * aTE.x;
        by += c.z * a.y - c.y * aTE.y;
        bz += c.z * a.z - c.y * aTE.z;
        bw += c.z * a.w - c.y * aTE.w;

        float dot = aTE.x * a.x + aTE.y * a.y + aTE.z * a.z + aTE.w * a.w;
        float sq  = a.x * a.x + a.y * a.y + a.z * a.z + a.w * a.w;
        tr += 2.0f * c.x * dot - c.w * sq;
    }

    // per-wave trace partial: shuffle-reduce, lane 0 stores. No LDS, no barrier.
    for (int off = 32; off > 0; off >>= 1)
        tr += __shfl_down(tr, off);
    if ((t & 63) == 0) {
        int slot = (blockIdx.y * VBLK + blockIdx.x) * WPB + (t >> 6);
        tr_partial[slot] = tr;
    }

    // bTE partials -> device-scope atomics, issued last: retire after endpgm,
    // overlapped with subsequent blocks (no barrier forces a drain).
    int v = v4 * 4;
    atomicAdd(&out[OFF_B + v + 0], bx);
    atomicAdd(&out[OFF_B + v + 1], by);
    atomicAdd(&out[OFF_B + v + 2], bz);
    atomicAdd(&out[OFF_B + v + 3], bw);
}

__global__ __launch_bounds__(TPB) void fin_k(
    const float* __restrict__ tr_partial,
    const float* __restrict__ varvbarTE,
    float* __restrict__ out)
{
    int t = threadIdx.x;
    float s = 0.f;
    for (int i = t; i < NSLOT; i += TPB) s += tr_partial[i];
    for (int off = 32; off > 0; off >>= 1)
        s += __shfl_down(s, off);
    __shared__ float wsum[TPB / 64];
    if ((t & 63) == 0) wsum[t >> 6] = s;
    __syncthreads();
    if (t == 0) {
        float tr = wsum[0] + wsum[1] + wsum[2] + wsum[3];
        out[OFF_SIG] = (varvbarTE[0] - tr) / (float)NV;
    }
}

extern "C" void kernel_launch(void* const* d_in, const int* in_sizes, int n_in,
                              void* d_out, int out_size, void* d_ws, size_t ws_size,
                              hipStream_t stream) {
    const float* muvTE       = (const float*)d_in[0];
    const float* varvhTE     = (const float*)d_in[1];
    const float* varh_diagTE = (const float*)d_in[2];
    const float* varh_diag   = (const float*)d_in[3];
    const float* muh         = (const float*)d_in[4];
    const float* varvh       = (const float*)d_in[5];
    const float* muhTE       = (const float*)d_in[6];
    const float* varvbarTE   = (const float*)d_in[7];
    float* out        = (float*)d_out;
    float* tr_partial = (float*)d_ws;   // NSLOT floats = 64 KB

    init_k<<<NV / TPB, TPB, 0, stream>>>(muvTE, varh_diagTE, muhTE, out);
    main_k<<<dim3(VBLK, HCH), TPB, 0, stream>>>(
        (const float4*)varvhTE, (const float4*)varvh,
        varh_diagTE, varh_diag, muh, muhTE, out, tr_partial);
    fin_k<<<1, TPB, 0, stream>>>(tr_partial, varvbarTE, out);
}

// Round 7
// 355.954 us; speedup vs baseline: 1.0181x; 1.0181x over previous
//
#include <hip/hip_runtime.h>

#define NV 8192
#define NH 4096
#define TPB 256
#define HPB 8                      // h rows per block: 16 float4 loads per thread
#define HCH (NH / HPB)             // 512 h-chunks (gridDim.y)
#define ROW4 (NV / 4)              // 2048 float4 per row
#define VBLK (ROW4 / TPB)          // 8 blocks in x
#define WPB (TPB / 64)             // 4 waves per block
#define NSLOT (VBLK * HCH * WPB)   // 16384 per-wave trace partials (64 KB ws)

typedef float f32x4 __attribute__((ext_vector_type(4)));

// output layout (flat float offsets, reference return order)
#define OFF_B   ((size_t)0)
#define OFF_WT  ((size_t)NV)
#define OFF_SIG ((size_t)NV + (size_t)NH * (size_t)NV)
#define OFF_MUH (OFF_SIG + 1)
#define OFF_VHD (OFF_MUH + NH)

__global__ __launch_bounds__(TPB) void init_k(
    const float* __restrict__ muvTE,
    const float* __restrict__ varh_diagTE,
    const float* __restrict__ muhTE,
    float* __restrict__ out)
{
    int i = blockIdx.x * TPB + threadIdx.x;     // grid covers NV
    if (i < NV) out[OFF_B + i] = muvTE[i];
    if (i < NH) {
        out[OFF_MUH + i] = muhTE[i];
        out[OFF_VHD + i] = varh_diagTE[i];
    }
}

// R6 structure frozen (barrier-free, LDS-free, 16 laundered loads in flight).
// SINGLE CHANGE vs R6: wtTE written with PLAIN stores, not nontemporal.
// Theory: nt stores ack from memory-side (~900cy) vs L2 (~200cy) and clog the
// per-CU shared VMEM queue, back-pressuring load issue — the round-invariant
// that pinned BW at ~2.5 TB/s through every body-level ablation (R0-R6).
__global__ __launch_bounds__(TPB, 4) void main_k(
    const float4* __restrict__ varvhTE4,
    const float4* __restrict__ varvh4,
    const float* __restrict__ varh_diagTE,
    const float* __restrict__ varh_diag,
    const float* __restrict__ muh,
    const float* __restrict__ muhTE,
    float* __restrict__ out,
    float* __restrict__ tr_partial)
{
    const int t  = threadIdx.x;
    const int h0 = blockIdx.y * HPB;
    const int v4 = blockIdx.x * TPB + t;        // float4 column index
    f32x4* wt4 = (f32x4*)(out + OFF_WT);
    const size_t base = (size_t)h0 * ROW4 + (size_t)v4;

    // ---- phase 1: issue ALL 16 vector loads (64 data VGPRs) ----
    float4 aTE_r[HPB], a_r[HPB];
    #pragma unroll
    for (int r = 0; r < HPB; ++r) {
        size_t idx = base + (size_t)r * ROW4;
        aTE_r[r] = varvhTE4[idx];
        a_r[r]   = varvh4[idx];
    }

    // per-h coefficients {inv, inv*muh, d*muh - inv*muhTE, d}: block-uniform
    // scalar loads + VALU, hidden under the vmem latency.
    float4 cf[HPB];
    #pragma unroll
    for (int r = 0; r < HPB; ++r) {
        float inv = 1.0f / varh_diag[h0 + r];
        float d   = inv * varh_diagTE[h0 + r] * inv;
        float m   = muh[h0 + r];
        cf[r] = make_float4(inv, inv * m, d * m - inv * muhTE[h0 + r], d);
    }

    // loads may not sink below; compute consumes laundered defs (counted vmcnt)
    asm volatile("" ::: "memory");
    #pragma unroll
    for (int r = 0; r < HPB; ++r) {
        asm volatile("" : "+v"(aTE_r[r].x), "+v"(aTE_r[r].y),
                          "+v"(aTE_r[r].z), "+v"(aTE_r[r].w));
        asm volatile("" : "+v"(a_r[r].x), "+v"(a_r[r].y),
                          "+v"(a_r[r].z), "+v"(a_r[r].w));
    }

    // ---- phase 2: compute + store ----
    float bx = 0.f, by = 0.f, bz = 0.f, bw = 0.f;
    float tr = 0.f;

    #pragma unroll
    for (int r = 0; r < HPB; ++r) {
        float4 c   = cf[r];
        float4 aTE = aTE_r[r];
        float4 a   = a_r[r];
        size_t idx = base + (size_t)r * ROW4;

        f32x4 w;
        w.x = c.x * aTE.x - c.w * a.x;
        w.y = c.x * aTE.y - c.w * a.y;
        w.z = c.x * aTE.z - c.w * a.z;
        w.w = c.x * aTE.w - c.w * a.w;
        wt4[idx] = w;                           // PLAIN store (the experiment)

        bx += c.z * a.x - c.y * aTE.x;
        by += c.z * a.y - c.y * aTE.y;
        bz += c.z * a.z - c.y * aTE.z;
        bw += c.z * a.w - c.y * aTE.w;

        float dot = aTE.x * a.x + aTE.y * a.y + aTE.z * a.z + aTE.w * a.w;
        float sq  = a.x * a.x + a.y * a.y + a.z * a.z + a.w * a.w;
        tr += 2.0f * c.x * dot - c.w * sq;
    }

    // per-wave trace partial: shuffle-reduce, lane 0 stores. No LDS, no barrier.
    for (int off = 32; off > 0; off >>= 1)
        tr += __shfl_down(tr, off);
    if ((t & 63) == 0) {
        int slot = (blockIdx.y * VBLK + blockIdx.x) * WPB + (t >> 6);
        tr_partial[slot] = tr;
    }

    // bTE partials -> device-scope atomics, issued last (retire after endpgm)
    int v = v4 * 4;
    atomicAdd(&out[OFF_B + v + 0], bx);
    atomicAdd(&out[OFF_B + v + 1], by);
    atomicAdd(&out[OFF_B + v + 2], bz);
    atomicAdd(&out[OFF_B + v + 3], bw);
}

__global__ __launch_bounds__(TPB) void fin_k(
    const float* __restrict__ tr_partial,
    const float* __restrict__ varvbarTE,
    float* __restrict__ out)
{
    int t = threadIdx.x;
    float s = 0.f;
    for (int i = t; i < NSLOT; i += TPB) s += tr_partial[i];
    for (int off = 32; off > 0; off >>= 1)
        s += __shfl_down(s, off);
    __shared__ float wsum[TPB / 64];
    if ((t & 63) == 0) wsum[t >> 6] = s;
    __syncthreads();
    if (t == 0) {
        float tr = wsum[0] + wsum[1] + wsum[2] + wsum[3];
        out[OFF_SIG] = (varvbarTE[0] - tr) / (float)NV;
    }
}

extern "C" void kernel_launch(void* const* d_in, const int* in_sizes, int n_in,
                              void* d_out, int out_size, void* d_ws, size_t ws_size,
                              hipStream_t stream) {
    const float* muvTE       = (const float*)d_in[0];
    const float* varvhTE     = (const float*)d_in[1];
    const float* varh_diagTE = (const float*)d_in[2];
    const float* varh_diag   = (const float*)d_in[3];
    const float* muh         = (const float*)d_in[4];
    const float* varvh       = (const float*)d_in[5];
    const float* muhTE       = (const float*)d_in[6];
    const float* varvbarTE   = (const float*)d_in[7];
    float* out        = (float*)d_out;
    float* tr_partial = (float*)d_ws;   // NSLOT floats = 64 KB

    init_k<<<NV / TPB, TPB, 0, stream>>>(muvTE, varh_diagTE, muhTE, out);
    main_k<<<dim3(VBLK, HCH), TPB, 0, stream>>>(
        (const float4*)varvhTE, (const float4*)varvh,
        varh_diagTE, varh_diag, muh, muhTE, out, tr_partial);
    fin_k<<<1, TPB, 0, stream>>>(tr_partial, varvbarTE, out);
}